// Round 1
// baseline (135.959 us; speedup 1.0000x reference)
//
#include <hip/hip_runtime.h>
#include <hip/hip_bf16.h>
#include <math.h>

#define IN_DIM 256
#define HD     512   // NUM_HEADS * OUT_DIM
#define NHEADS 8
#define DH     64
#define NSEQ   1024
#define BATCH  8

#define QSCALE 0.18033688011112042f   // 0.125 * log2(e): S in log2 domain

typedef unsigned short u16;
typedef unsigned int   u32;
typedef short bf16x8 __attribute__((ext_vector_type(8)));
typedef float f32x4  __attribute__((ext_vector_type(4)));
typedef float f32x16 __attribute__((ext_vector_type(16)));
typedef unsigned int u32x2 __attribute__((ext_vector_type(2)));

#if __has_builtin(__builtin_amdgcn_exp2f)
#define EXP2(x) __builtin_amdgcn_exp2f(x)
#else
#define EXP2(x) __expf(0.69314718056f * (x))
#endif

static __device__ __forceinline__ u16 f2bf(float x) {
    u32 u = __builtin_bit_cast(u32, x);
    u += 0x7FFFu + ((u >> 16) & 1u);     // RNE
    return (u16)(u >> 16);
}
static __device__ __forceinline__ u32 pk(u16 a, u16 b) {
    return (u32)a | ((u32)b << 16);
}
static __device__ __forceinline__ u32 cvtpk(float a, float b) {
    __hip_bfloat162 t = __float22bfloat162_rn(make_float2(a, b));
    u32 r; __builtin_memcpy(&r, &t, 4);
    return r;
}
// 16 bf16 (two uint4) -> f32x16 C-init
static __device__ __forceinline__ f32x16 maskinit(uint4 a, uint4 b) {
    f32x16 c;
    u32 ws[8] = {a.x, a.y, a.z, a.w, b.x, b.y, b.z, b.w};
#pragma unroll
    for (int i = 0; i < 8; ++i) {
        c[2 * i]     = __builtin_bit_cast(float, ws[i] << 16);
        c[2 * i + 1] = __builtin_bit_cast(float, ws[i] & 0xFFFF0000u);
    }
    return c;
}

// permlane32_swap: a' = [a_lo | b_lo], b' = [a_hi | b_hi] (32-lane rows)
static __device__ __forceinline__ void pswap(u32 &a, u32 &b) {
#if __has_builtin(__builtin_amdgcn_permlane32_swap)
    u32x2 r = __builtin_amdgcn_permlane32_swap(a, b, false, false);
    a = r.x; b = r.y;
#else
    const bool hi = (threadIdx.x & 32) != 0;
    u32 as = (u32)__shfl_xor((int)a, 32, 64);
    u32 bs = (u32)__shfl_xor((int)b, 32, 64);
    u32 na = hi ? bs : a;
    u32 nb = hi ? b  : as;
    a = na; b = nb;
#endif
}

#define MFMA32(a, b, c) __builtin_amdgcn_mfma_f32_32x32x16_bf16(a, b, c, 0, 0, 0)

// exp2 of two key-tiles of one q-tile, tree-sum, pack to bf16, and exchange
// halves in-register so pb[s] is the B-frag for k-step s (replaces Ps LDS
// round-trip: write granules t*4+2h+{0,1}, read granules s*2+h).
static __device__ __forceinline__ float sm_pack(const f32x16 s0, const f32x16 s1,
                                                bf16x8* pb) {
    float p0[16], p1[16];
#pragma unroll
    for (int r = 0; r < 16; ++r) p0[r] = EXP2(s0[r]);
#pragma unroll
    for (int r = 0; r < 16; ++r) p1[r] = EXP2(s1[r]);
    float t0 = (((p0[0] + p0[1]) + (p0[2] + p0[3])) + ((p0[4] + p0[5]) + (p0[6] + p0[7])))
             + (((p0[8] + p0[9]) + (p0[10] + p0[11])) + ((p0[12] + p0[13]) + (p0[14] + p0[15])));
    float t1 = (((p1[0] + p1[1]) + (p1[2] + p1[3])) + ((p1[4] + p1[5]) + (p1[6] + p1[7])))
             + (((p1[8] + p1[9]) + (p1[10] + p1[11])) + ((p1[12] + p1[13]) + (p1[14] + p1[15])));
    uint4 w0, w1, w2, w3;
    w0.x = cvtpk(p0[0], p0[1]);   w0.y = cvtpk(p0[2], p0[3]);
    w0.z = cvtpk(p0[4], p0[5]);   w0.w = cvtpk(p0[6], p0[7]);
    w1.x = cvtpk(p0[8], p0[9]);   w1.y = cvtpk(p0[10], p0[11]);
    w1.z = cvtpk(p0[12], p0[13]); w1.w = cvtpk(p0[14], p0[15]);
    w2.x = cvtpk(p1[0], p1[1]);   w2.y = cvtpk(p1[2], p1[3]);
    w2.z = cvtpk(p1[4], p1[5]);   w2.w = cvtpk(p1[6], p1[7]);
    w3.x = cvtpk(p1[8], p1[9]);   w3.y = cvtpk(p1[10], p1[11]);
    w3.z = cvtpk(p1[12], p1[13]); w3.w = cvtpk(p1[14], p1[15]);
    pswap(w0.x, w1.x); pswap(w0.y, w1.y); pswap(w0.z, w1.z); pswap(w0.w, w1.w);
    pswap(w2.x, w3.x); pswap(w2.y, w3.y); pswap(w2.z, w3.z); pswap(w2.w, w3.w);
    pb[0] = __builtin_bit_cast(bf16x8, w0);
    pb[1] = __builtin_bit_cast(bf16x8, w1);
    pb[2] = __builtin_bit_cast(bf16x8, w2);
    pb[3] = __builtin_bit_cast(bf16x8, w3);
    return t0 + t1;
}

// ============================================================
// W transpose: 96 blocks. W [K=256][N=512] fp32 -> Wt [N][K] bf16 (x3)
// ============================================================
__global__ __launch_bounds__(256)
void wtrans_kernel(const float* __restrict__ Wq, const float* __restrict__ Wk,
                   const float* __restrict__ Wv, u16* __restrict__ Wt)
{
    __shared__ float tile[64 * 65];
    const int bid = blockIdx.x, tid = threadIdx.x;
    const int k0 = (bid & 3) * 64, n0 = ((bid >> 2) & 7) * 64, wsel = bid >> 5;
    const float* W = (wsel == 0) ? Wq : (wsel == 1) ? Wk : Wv;
    u16* Out = Wt + (size_t)wsel * HD * IN_DIM;

    const int r = tid >> 2, c0 = (tid & 3) * 16;
#pragma unroll
    for (int j = 0; j < 16; j += 4) {
        float4 v = *(const float4*)(W + (size_t)(k0 + r) * HD + n0 + c0 + j);
        tile[r * 65 + c0 + j + 0] = v.x; tile[r * 65 + c0 + j + 1] = v.y;
        tile[r * 65 + c0 + j + 2] = v.z; tile[r * 65 + c0 + j + 3] = v.w;
    }
    __syncthreads();
    const int n = tid >> 2, ks = (tid & 3) * 16;
    u16 o[16];
#pragma unroll
    for (int j = 0; j < 16; ++j) o[j] = f2bf(tile[(ks + j) * 65 + n]);
    uint4 u0, u1;
    u0.x = pk(o[0], o[1]);   u0.y = pk(o[2], o[3]);
    u0.z = pk(o[4], o[5]);   u0.w = pk(o[6], o[7]);
    u1.x = pk(o[8], o[9]);   u1.y = pk(o[10], o[11]);
    u1.z = pk(o[12], o[13]); u1.w = pk(o[14], o[15]);
    u16* dst = Out + (size_t)(n0 + n) * IN_DIM + k0 + ks;
    *(uint4*)(dst) = u0;
    *(uint4*)(dst + 8) = u1;
}

// ============================================================
// Fused QKV GEMM + mask build, grid (128, 10):
//  y<8:  GEMM m-tile 64 x head y — 32x32x16 MFMA, acc 48 VGPR,
//        wave w owns (mh=w&1, nh=w>>1) 32x32 tile of Q,K,V.
//  y>=8: adj -> Madd2[q][64*ch + cpos(c)] bf16 {0,-3.39e38}
//        cpos(c) = 32*(c>>5) + 16*((c>>2)&1) + 4*((c>>3)&3) + (c&3)
// ============================================================
__global__ __launch_bounds__(256, 4)
void gemm_mask_kernel(const float* __restrict__ h, const u16* __restrict__ Wt,
                      const int* __restrict__ adj,
                      const float* __restrict__ bq, const float* __restrict__ bk,
                      const float* __restrict__ bv,
                      u16* __restrict__ Qg, u16* __restrict__ Kg,
                      u16* __restrict__ Vtg, u16* __restrict__ Madd2)
{
    __shared__ u16 pool[64 * 64 + 3 * 64 * 64];   // 32 KB
    const int tid = threadIdx.x;

    if (blockIdx.y >= 8) {
        // ---- adjacency -> bf16 additive mask, cpos-permuted cols ----
        int* tile = (int*)pool;              // [64][65] ints
        const int abid = (blockIdx.y - 8) * 128 + blockIdx.x;   // 0..255
        const int tR = abid >> 4, tC = abid & 15;   // q-tile, key-chunk
        const int r = tid >> 2, cg = (tid & 3) * 16;
        const int* src = adj + (size_t)(tR * 64 + r) * NSEQ + tC * 64 + cg;
#pragma unroll
        for (int j = 0; j < 16; j += 4) {
            int4 a = *(const int4*)(src + j);
            tile[r * 65 + cg + j + 0] = a.x; tile[r * 65 + cg + j + 1] = a.y;
            tile[r * 65 + cg + j + 2] = a.z; tile[r * 65 + cg + j + 3] = a.w;
        }
        __syncthreads();
        const int q = tid >> 2, p0 = (tid & 3) * 16;
        u16 o[16];
#pragma unroll
        for (int j = 0; j < 16; ++j) {
            const int p = p0 + j;
            const int c = 32 * (p >> 5) + (p & 3) + 4 * ((p >> 4) & 1) + 8 * ((p >> 2) & 3);
            o[j] = (tile[q * 65 + c] == 0) ? (u16)0xFF7F : (u16)0;
        }
        uint4 u0, u1;
        u0.x = pk(o[0], o[1]);   u0.y = pk(o[2], o[3]);
        u0.z = pk(o[4], o[5]);   u0.w = pk(o[6], o[7]);
        u1.x = pk(o[8], o[9]);   u1.y = pk(o[10], o[11]);
        u1.z = pk(o[12], o[13]); u1.w = pk(o[14], o[15]);
        u16* dst = Madd2 + (size_t)(tR * 64 + q) * NSEQ + tC * 64 + p0;
        *(uint4*)(dst) = u0;
        *(uint4*)(dst + 8) = u1;
        return;
    }

    // ---------------- GEMM branch (32x32x16) ----------------
    u16* As = pool;
    u16* Bs = pool + 64 * 64;

    const int m0 = blockIdx.x * 64;
    const int hh = blockIdx.y;
    const int n0 = hh * 64;

    const int w = tid >> 6, lane = tid & 63;
    const int l31 = lane & 31, half = lane >> 5;
    const int mh = w & 1, nh = w >> 1;
    const int s7 = l31 & 7;

    f32x16 acc[3] = {};   // Q, K, V 32x32 tiles

    const int arw = tid >> 2, acg = (tid & 3) * 2;
    const int brw = tid & 63, bgrp = tid >> 6;
    const float* srcA = h + (size_t)(m0 + arw) * IN_DIM;

    for (int kk = 0; kk < IN_DIM; kk += 64) {
        __syncthreads();
#pragma unroll
        for (int g = 0; g < 2; ++g) {
            const float* p = srcA + kk + (acg + g) * 8;
            float4 v0 = *(const float4*)(p);
            float4 v1 = *(const float4*)(p + 4);
            uint4 u;
            u.x = cvtpk(v0.x, v0.y); u.y = cvtpk(v0.z, v0.w);
            u.z = cvtpk(v1.x, v1.y); u.w = cvtpk(v1.z, v1.w);
            *(uint4*)&As[arw * 64 + (((acg + g) ^ (arw & 7)) * 8)] = u;
        }
#pragma unroll
        for (int i = 0; i < 6; ++i) {
            const int gc = bgrp * 6 + i;
            const int wh = gc >> 3, c8 = gc & 7;
            *(uint4*)&Bs[wh * 4096 + brw * 64 + ((c8 ^ (brw & 7)) * 8)] =
                *(const uint4*)(Wt + (size_t)wh * HD * IN_DIM +
                                (size_t)(n0 + brw) * IN_DIM + kk + c8 * 8);
        }
        __syncthreads();
        const int arow = (32 * mh + l31) * 64;
        const int brow = (32 * nh + l31) * 64;
#pragma unroll
        for (int s = 0; s < 4; ++s) {
            const int g = ((s * 2 + half) ^ s7) * 8;
            bf16x8 a = *(const bf16x8*)&As[arow + g];
#pragma unroll
            for (int wh = 0; wh < 3; ++wh) {
                bf16x8 b = *(const bf16x8*)&Bs[wh * 4096 + brow + g];
                acc[wh] = __builtin_amdgcn_mfma_f32_32x32x16_bf16(a, b, acc[wh], 0, 0, 0);
            }
        }
    }

    // ---- Q and K epilogues: LDS re-tile, coalesced stores ----
    // C-layout: col = 32*nh + l31, row = 32*mh + 4*half + (r&3) + 8*(r>>2)
    for (int which = 0; which < 2; ++which) {
        u16* T = pool;   // [64][72]
        const float* bias = (which == 0) ? bq : bk;
        u16* Out = (which == 0) ? Qg : Kg;
        const float scale = (which == 0) ? QSCALE : 1.0f;
        const float bvv = bias[n0 + 32 * nh + l31];
        __syncthreads();
#pragma unroll
        for (int r = 0; r < 16; ++r) {
            const int row = 32 * mh + 4 * half + (r & 3) + 8 * (r >> 2);
            T[row * 72 + 32 * nh + l31] = f2bf((acc[which][r] + bvv) * scale);
        }
        __syncthreads();
        const int row = tid >> 2, qc = (tid & 3) * 16;
        u16* dst = Out + (size_t)(m0 + row) * HD + n0 + qc;
        const u16* srcT = &T[row * 72 + qc];
        *(uint4*)(dst)     = *(const uint4*)(srcT);
        *(uint4*)(dst + 8) = *(const uint4*)(srcT + 8);
    }

    // ---- V epilogue: transpose + cpos permutation ----
    // m = 32*mh + 4*half + (r&3) + 8*(r>>2)  ->  pos(m) = 32*mh + 16*half + 4*(r>>2) + (r&3)
    {
        u16* T = pool;   // [64][72]  [d][pos]
        const int d = 32 * nh + l31;
        const float bvv = bv[n0 + d];
        __syncthreads();
#pragma unroll
        for (int g = 0; g < 4; ++g) {
            ushort4 o;
            o.x = f2bf(acc[2][4 * g + 0] + bvv);
            o.y = f2bf(acc[2][4 * g + 1] + bvv);
            o.z = f2bf(acc[2][4 * g + 2] + bvv);
            o.w = f2bf(acc[2][4 * g + 3] + bvv);
            *(ushort4*)&T[d * 72 + 32 * mh + 16 * half + 4 * g] = o;
        }
        __syncthreads();
        const int b = m0 >> 10, nloc = m0 & 1023;
        const int dd = tid >> 2, c = (tid & 3) * 16;
        u16* dst = Vtg + ((size_t)(b * NHEADS + hh) * DH + dd) * NSEQ + nloc + c;
        *(uint4*)(dst)     = *(uint4*)&T[dd * 72 + c];
        *(uint4*)(dst + 8) = *(uint4*)&T[dd * 72 + c + 8];
    }
}

// ============================================================
// Fused masked attention, 32x32x16 MFMA, no-max softmax.
// qrep=2: each wave owns 64 q rows (two 32-wide B-frag tiles) so the
// shared K/V A-frag LDS reads amortize over 2x the MFMAs; P stays in
// registers via v_permlane32_swap_b32 (no Ps LDS round-trip).
// grid (64 bh, 4 qt), 256 thr (4 waves x 64 q-rows), 1 block/CU.
// K/V prefetch distance 2 (two static reg sets, loop unrolled x2).
// ============================================================
__global__ __launch_bounds__(256, 1)
void attn_kernel(const u16* __restrict__ Madd2, const u16* __restrict__ Qg,
                 const u16* __restrict__ Kg, const u16* __restrict__ Vtg,
                 float* __restrict__ out)
{
    __shared__ u16 Ks[2][64 * 64];
    __shared__ u16 Vs[2][64 * 64];     // [d][cpos(m)]

    const int tid = threadIdx.x;
    const int w = tid >> 6, lane = tid & 63;
    const int l31 = lane & 31, half = lane >> 5;
    const int bh = blockIdx.x, qt = blockIdx.y;
    const int b = bh >> 3;
    const int n0 = qt * 256;
    const size_t rowbase = (size_t)b * NSEQ;
    const int colbase = (bh & 7) * DH;
    const int q7 = l31 & 7;
    const int qA = w * 64 + l31;          // block-local q row, tile A
    const int qB = qA + 32;               // tile B

    // Q B-frags (bf16, pre-scaled): B[k][q=l31]
    const u16* qga = Qg + (rowbase + n0 + qA) * HD + colbase;
    const u16* qgb = Qg + (rowbase + n0 + qB) * HD + colbase;
    bf16x8 qbA[4], qbB[4];
#pragma unroll
    for (int s = 0; s < 4; ++s) {
        qbA[s] = *(const bf16x8*)(qga + s * 16 + half * 8);
        qbB[s] = *(const bf16x8*)(qgb + s * 16 + half * 8);
    }

    // staging: 256 thr -> 64 rows x 4 granule-pairs of K and V
    const int srow = tid >> 2, cp = (tid & 3) * 2;
    const int swc0 = ((cp ^ (srow & 7)) * 8), swc1 = (((cp + 1) ^ (srow & 7)) * 8);
    const u16* kgp = Kg + (rowbase + srow) * HD + colbase + cp * 8;
    const u16* vgp = Vtg + ((size_t)bh * DH + srow) * NSEQ + cp * 8;
    // mask rows (cols cpos-permuted): lane's own two q rows
    const u16* mrowA = Madd2 + (size_t)(n0 + qA) * NSEQ + half * 16;
    const u16* mrowB = Madd2 + (size_t)(n0 + qB) * NSEQ + half * 16;

    // mask regs, chunk 0
    uint4 mA0a = *(const uint4*)(mrowA);
    uint4 mA0b = *(const uint4*)(mrowA + 8);
    uint4 mA1a = *(const uint4*)(mrowA + 32);
    uint4 mA1b = *(const uint4*)(mrowA + 40);
    uint4 mB0a = *(const uint4*)(mrowB);
    uint4 mB0b = *(const uint4*)(mrowB + 8);
    uint4 mB1a = *(const uint4*)(mrowB + 32);
    uint4 mB1b = *(const uint4*)(mrowB + 40);

    // K/V reg sets: s0 holds chunk 0 (staged immediately), s1 holds chunk 1
    uint4 s0k0, s0k1, s0v0, s0v1;
    uint4 s1k0, s1k1, s1v0, s1v1;
    s0k0 = *(const uint4*)kgp;       s0k1 = *(const uint4*)(kgp + 8);
    s0v0 = *(const uint4*)vgp;       s0v1 = *(const uint4*)(vgp + 8);
    *(uint4*)&Ks[0][srow * 64 + swc0] = s0k0;
    *(uint4*)&Ks[0][srow * 64 + swc1] = s0k1;
    *(uint4*)&Vs[0][srow * 64 + swc0] = s0v0;
    *(uint4*)&Vs[0][srow * 64 + swc1] = s0v1;
    s1k0 = *(const uint4*)(kgp + (size_t)64 * HD);
    s1k1 = *(const uint4*)(kgp + (size_t)64 * HD + 8);
    s1v0 = *(const uint4*)(vgp + 64);
    s1v1 = *(const uint4*)(vgp + 64 + 8);
    __syncthreads();

    float lA = 0.f, lB = 0.f;
    f32x16 OA0 = {}, OA1 = {}, OB0 = {}, OB1 = {};

#define CHUNK(CH, CUR, KW, KL)                                                 \
    {                                                                          \
        f32x16 sA0 = maskinit(mA0a, mA0b);                                     \
        f32x16 sA1 = maskinit(mA1a, mA1b);                                     \
        f32x16 sB0 = maskinit(mB0a, mB0b);                                     \
        f32x16 sB1 = maskinit(mB1a, mB1b);                                     \
        if ((CH) < 15) {                                                       \
            const u16* ma = mrowA + ((CH) + 1) * 64;                           \
            const u16* mb = mrowB + ((CH) + 1) * 64;                           \
            mA0a = *(const uint4*)(ma);      mA0b = *(const uint4*)(ma + 8);   \
            mA1a = *(const uint4*)(ma + 32); mA1b = *(const uint4*)(ma + 40);  \
            mB0a = *(const uint4*)(mb);      mB0b = *(const uint4*)(mb + 8);   \
            mB1a = *(const uint4*)(mb + 32); mB1b = *(const uint4*)(mb + 40);  \
        }                                                                      \
        _Pragma("unroll")                                                      \
        for (int s = 0; s < 4; ++s) {                                          \
            const int g = ((s * 2 + half) ^ q7) * 8;                           \
            bf16x8 ka0 = *(const bf16x8*)&Ks[CUR][l31 * 64 + g];               \
            bf16x8 ka1 = *(const bf16x8*)&Ks[CUR][(32 + l31) * 64 + g];        \
            sA0 = MFMA32(ka0, qbA[s], sA0);                                    \
            sA1 = MFMA32(ka1, qbA[s], sA1);                                    \
            sB0 = MFMA32(ka0, qbB[s], sB0);                                    \
            sB1 = MFMA32(ka1, qbB[s], sB1);                                    \
        }                                                                      \
        if ((CH) < 15) {                                                       \
            *(uint4*)&Ks[1 - (CUR)][srow * 64 + swc0] = KW##k0;                \
            *(uint4*)&Ks[1 - (CUR)][srow * 64 + swc1] = KW##k1;                \
            *(uint4*)&Vs[1 - (CUR)][srow * 64 + swc0] = KW##v0;                \
            *(uint4*)&Vs[1 - (CUR)][srow * 64 + swc1] = KW##v1;                \
        }                                                                      \
        if ((CH) < 14) {                                                       \
            const size_t ko = (size_t)((CH) + 2) * 64 * HD;                    \
            const int    vo = ((CH) + 2) * 64;                                 \
            KL##k0 = *(const uint4*)(kgp + ko);                                \
            KL##k1 = *(const uint4*)(kgp + ko + 8);                            \
            KL##v0 = *(const uint4*)(vgp + vo);                                \
            KL##v1 = *(const uint4*)(vgp + vo + 8);                            \
        }                                                                      \
        bf16x8 pbA[4], pbB[4];                                                 \
        lA += sm_pack(sA0, sA1, pbA);                                          \
        lB += sm_pack(sB0, sB1, pbB);                                          \
        _Pragma("unroll")                                                      \
        for (int s = 0; s < 4; ++s) {                                          \
            const int g = ((s * 2 + half) ^ q7) * 8;                           \
            bf16x8 va0 = *(const bf16x8*)&Vs[CUR][l31 * 64 + g];               \
            bf16x8 va1 = *(const bf16x8*)&Vs[CUR][(32 + l31) * 64 + g];        \
            OA0 = MFMA32(va0, pbA[s], OA0);                                    \
            OA1 = MFMA32(va1, pbA[s], OA1);                                    \
            OB0 = MFMA32(va0, pbB[s], OB0);                                    \
            OB1 = MFMA32(va1, pbB[s], OB1);                                    \
        }                                                                      \
        __syncthreads();                                                       \
    }

    for (int ch = 0; ch < 16; ch += 2) {
        CHUNK(ch,     0, s1, s0)
        CHUNK(ch + 1, 1, s0, s1)
    }
#undef CHUNK

    // l: lanes l and l+32 hold disjoint key subsets of the same q
    lA += __shfl_xor(lA, 32, 64);
    lB += __shfl_xor(lB, 32, 64);
    const float invA = 1.0f / lA;
    const float invB = 1.0f / lB;

    float* orowA = out + (rowbase + n0 + qA) * HD + colbase;
    float* orowB = out + (rowbase + n0 + qB) * HD + colbase;
#pragma unroll
    for (int g = 0; g < 4; ++g) {
        const int d0 = 4 * half + 8 * g;
        float4 a0, a1, b0, b1;
        a0.x = OA0[4 * g + 0] * invA; a0.y = OA0[4 * g + 1] * invA;
        a0.z = OA0[4 * g + 2] * invA; a0.w = OA0[4 * g + 3] * invA;
        a1.x = OA1[4 * g + 0] * invA; a1.y = OA1[4 * g + 1] * invA;
        a1.z = OA1[4 * g + 2] * invA; a1.w = OA1[4 * g + 3] * invA;
        b0.x = OB0[4 * g + 0] * invB; b0.y = OB0[4 * g + 1] * invB;
        b0.z = OB0[4 * g + 2] * invB; b0.w = OB0[4 * g + 3] * invB;
        b1.x = OB1[4 * g + 0] * invB; b1.y = OB1[4 * g + 1] * invB;
        b1.z = OB1[4 * g + 2] * invB; b1.w = OB1[4 * g + 3] * invB;
        *(float4*)(orowA + d0)      = a0;
        *(float4*)(orowA + 32 + d0) = a1;
        *(float4*)(orowB + d0)      = b0;
        *(float4*)(orowB + 32 + d0) = b1;
    }
}

// ============================================================
extern "C" void kernel_launch(void* const* d_in, const int* in_sizes, int n_in,
                              void* d_out, int out_size, void* d_ws, size_t ws_size,
                              hipStream_t stream) {
    const int*   adj = (const int*)d_in[0];
    const float* h   = (const float*)d_in[1];
    const float* Wq  = (const float*)d_in[2];
    const float* bq  = (const float*)d_in[3];
    const float* Wk  = (const float*)d_in[4];
    const float* bk  = (const float*)d_in[5];
    const float* Wv  = (const float*)d_in[6];
    const float* bv  = (const float*)d_in[7];
    float* outp = (float*)d_out;

    u16* Wt    = (u16*)d_ws;                                 // 3*512*256 u16
    u16* Qg    = Wt + (size_t)3 * HD * IN_DIM;               // 4 Mi u16 each
    u16* Kg    = Qg + (size_t)BATCH * NSEQ * HD;
    u16* Vtg   = Kg + (size_t)BATCH * NSEQ * HD;
    u16* Madd2 = Vtg + (size_t)BATCH * NSEQ * HD;            // 1 Mi u16
    (void)ws_size;

    wtrans_kernel<<<96, 256, 0, stream>>>(Wq, Wk, Wv, Wt);
    gemm_mask_kernel<<<dim3(BATCH * NSEQ / 64, 10), 256, 0, stream>>>(
        h, Wt, adj, bq, bk, bv, Qg, Kg, Vtg, Madd2);
    attn_kernel<<<dim3(BATCH * NHEADS, NSEQ / 256), 256, 0, stream>>>(
        Madd2, Qg, Kg, Vtg, outp);
}